// Round 6
// baseline (1633.140 us; speedup 1.0000x reference)
//
#include <hip/hip_runtime.h>

typedef _Float16 half8 __attribute__((ext_vector_type(8)));
typedef _Float16 half4v __attribute__((ext_vector_type(4)));
typedef float floatx4 __attribute__((ext_vector_type(4)));

// ---------------------------------------------------------------------------
// Decoder: 6 conv_transpose3d (JAX SAME, no kernel flip), fp16 MFMA.
// R11: MEASUREMENT ROUND. Real pipeline = R10 verbatim (207.8us). After the
// final output is written, 10 probe dispatches re-run each body x24 inside a
// single kernel so per-layer cost surfaces in rocprof's top-5 (dur/24).
// Probes write only dead/scratch buffers; every buffer is fully rewritten by
// the real pipeline each graph iteration, so correctness is unaffected.
// Headline dur_us is intentionally inflated this round.
// ---------------------------------------------------------------------------

__global__ __launch_bounds__(256) void pad_x_k(const float* __restrict__ X,
                                               _Float16* __restrict__ P) {
  int idx = blockIdx.x * 256 + threadIdx.x;   // P1: [5][5][5][1024]
  if (idx >= 125 * 1024) return;
  int c = idx & 1023;
  int r = idx >> 10;
  int px = r % 5, py = (r / 5) % 5, pz = r / 25;
  float v = 0.f;
  if (px >= 1 && py >= 1 && pz >= 1)
    v = X[c * 64 + (pz - 1) * 16 + (py - 1) * 4 + (px - 1)];  // NCDHW -> cl
  P[idx] = (_Float16)v;
}

// Reduce partials -> ReLU -> fp16 -> padded next-layer input (borders = 0).
template <int POS, int COUT, int S2IN, int NSPL, int PS>
__device__ __forceinline__ void red_body(int vb, const float* __restrict__ Pp,
                                         _Float16* __restrict__ P) {
  constexpr int C4 = COUT / 4;
  constexpr size_t U3 =
      S2IN ? (size_t)(POS / 2) * (POS / 2) * (POS / 2) : (size_t)POS * POS * POS;
  int idx = vb * 256 + threadIdx.x;
  if (idx >= PS * PS * PS * C4) return;
  const int co = (idx % C4) * 4;
  const int r = idx / C4;
  const int px = r % PS, py = (r / PS) % PS, pz = r / (PS * PS);
  const int ix = px - 1, iy = py - 1, iz = pz - 1;
  float4 s = make_float4(0.f, 0.f, 0.f, 0.f);
  if ((unsigned)ix < (unsigned)POS && (unsigned)iy < (unsigned)POS &&
      (unsigned)iz < (unsigned)POS) {
    int j0, j1;
    size_t upos;
    if (S2IN) {
      const int pf[8] = {0, 8, 12, 16, 18, 22, 24, 26};
      const int tc[8] = {8, 4, 4, 2, 4, 2, 2, 1};
      const int cls = ((iz & 1) << 2) | ((iy & 1) << 1) | (ix & 1);
      j0 = pf[cls] * NSPL;
      j1 = j0 + tc[cls] * NSPL;
      constexpr int U = POS / 2;
      upos = ((size_t)(iz >> 1) * U + (iy >> 1)) * U + (ix >> 1);
    } else {
      j0 = 0;
      j1 = NSPL;
      upos = ((size_t)iz * POS + iy) * POS + ix;
    }
    const float* base = Pp + upos * COUT + co;
    for (int j = j0; j < j1; j++) {
      float4 v = *(const float4*)(base + (size_t)j * U3 * COUT);
      s.x += v.x; s.y += v.y; s.z += v.z; s.w += v.w;
    }
  }
  half4v h;
  h[0] = (_Float16)fmaxf(s.x, 0.f);
  h[1] = (_Float16)fmaxf(s.y, 0.f);
  h[2] = (_Float16)fmaxf(s.z, 0.f);
  h[3] = (_Float16)fmaxf(s.w, 0.f);
  *(half4v*)(P + (size_t)idx * 4) = h;
}

template <int POS, int COUT, int S2IN, int NSPL, int PS>
__global__ __launch_bounds__(256) void red_k(const float* __restrict__ Pp,
                                             _Float16* __restrict__ P) {
  red_body<POS, COUT, S2IN, NSPL, PS>(blockIdx.x, Pp, P);
}

template <int POS, int COUT, int S2IN, int NSPL, int PS, int REP>
__global__ __launch_bounds__(256) void red_probe_k(const float* __restrict__ Pp,
                                                   _Float16* __restrict__ P) {
  for (int r = 0; r < REP; ++r) {
    red_body<POS, COUT, S2IN, NSPL, PS>(blockIdx.x, Pp, P);
    asm volatile("" ::: "memory");
  }
}

// red4 + P6 zero fused (real path).
__global__ __launch_bounds__(256) void red4z_k(const float* __restrict__ Q4,
                                               _Float16* __restrict__ P5,
                                               _Float16* __restrict__ P6) {
  if (blockIdx.x < 308) {
    red_body<16, 64, 0, 12, 17>(blockIdx.x, Q4, P5);
  } else {
    int i = (blockIdx.x - 308) * 256 + threadIdx.x;
    if (i < 157216) ((half8*)P6)[i] = half8{};
  }
}

// MFMA implicit-GEMM conv body (R10 verbatim, blockIdx -> args).
template <int CICHUNK, int CIN, int COUT, int NTILE, int TZ, int SOUTU,
          int PS, int SMODE, int TAPG, int STORE_MODE>
__device__ __forceinline__ void conv_body(int bxi, int byi, int bzi,
                                          const _Float16* __restrict__ P,
                                          const float* __restrict__ W,
                                          void* __restrict__ Optr) {
  constexpr int M = TZ * 16;               // 64 or 128
  constexpr bool S2 = (SMODE != 0);
  constexpr int MTZ = SOUTU / TZ;
  constexpr int MTXY = SOUTU / 4;
  constexpr int MT3 = MTZ * MTXY * MTXY;
  constexpr int KB = 32;
  constexpr int KP = 40;
  constexpr int KBI = CICHUNK / KB;
  constexpr int NCI = CIN / CICHUNK;
  constexpr int S = S2 ? 2 * SOUTU : SOUTU;
  constexpr int WM = (M == 128) ? 4 : 2;   // waves along m
  constexpr int NSUB = (WM == 4) ? (NTILE / 16) : (NTILE / 32);
  constexpr int BJ = KB * NTILE / 256;     // B fp32 loads per thread
  constexpr size_t U3 = (size_t)SOUTU * SOUTU * SOUTU;

  __shared__ __align__(16) _Float16 As[M][KP];
  __shared__ __align__(16) _Float16 Bs[NTILE][KP];

  int bx = bxi;
  int cls = 0, tap0 = 0, cig = bzi, jspl = 0;
  int p_toz = 0, p_toy = 0, p_tox = 0, p_wtap = 0;
  if (SMODE == 0) {
    const int tg = cig / NCI;
    cig -= tg * NCI;
    tap0 = tg * TAPG;
    jspl = bzi;                            // tg*NCI + cig
  } else if (SMODE == 1) {
    const int p = bx / MT3;
    bx -= p * MT3;
    jspl = p * NCI + cig;
    cls = (p >= 8) + (p >= 12) + (p >= 16) + (p >= 18) + (p >= 22) +
          (p >= 24) + (p >= 26);
    const int pf = cls == 0 ? 0 : cls == 1 ? 8 : cls == 2 ? 12
                 : cls == 3 ? 16 : cls == 4 ? 18 : cls == 5 ? 22
                 : cls == 6 ? 24 : 26;
    const int tl = p - pf;
    const int lz = (cls >> 2) & 1, ly = (cls >> 1) & 1, lx = cls & 1;
    const int shx = lx ? 0 : 1, shy = ly ? 0 : 1;
    const int iz = tl >> (shx + shy);
    const int rem = tl & ((1 << (shx + shy)) - 1);
    const int iy = rem >> shx;
    const int ix = rem & ((1 << shx) - 1);
    p_toz = lz ? 1 : iz;
    p_toy = ly ? 1 : iy;
    p_tox = lx ? 1 : ix;
    const int wz = lz ? 1 : 2 * iz, wy = ly ? 1 : 2 * iy,
              wx = lx ? 1 : 2 * ix;
    p_wtap = (wz * 3 + wy) * 3 + wx;
  } else {
    cls = bx / MT3;
    bx -= cls * MT3;
  }
  const int clz = (cls >> 2) & 1, cly = (cls >> 1) & 1, clx = cls & 1;

  const int u0z = (bx / (MTXY * MTXY)) * TZ;
  const int u0y = ((bx / MTXY) % MTXY) * 4;
  const int u0x = (bx % MTXY) * 4;
  const int n_base = byi * NTILE;

  const int t = threadIdx.x;
  const int lane = t & 63;
  const int wave = t >> 6;

  const int skq = t & 3;
  const int sp = t >> 2;
  const int spx = sp & 3, spy = (sp >> 2) & 3, spz = sp >> 4;
  const int nB = t & (NTILE - 1);
  const int k0B = (t / NTILE) * BJ;
  const int m0w = (WM == 4) ? wave * 32 : (wave >> 1) * 32;
  const int n0w = (WM == 4) ? 0 : (wave & 1) * 32;
  const int fr = lane & 15;
  const int fq = lane >> 4;

  const int cz = S2 ? (clz ? 1 : 2) : 3;
  const int cy = S2 ? (cly ? 1 : 2) : 3;
  const int cx = S2 ? (clx ? 1 : 2) : 3;
  const int shx2 = clx ? 0 : 1, shy2 = cly ? 0 : 1;

  int NIT;
  if (SMODE == 0) NIT = TAPG * KBI;
  else if (SMODE == 1) NIT = KBI;
  else NIT = cz * cy * cx * KBI;

  floatx4 acc[2][NSUB];
#pragma unroll
  for (int i = 0; i < 2; i++)
#pragma unroll
    for (int s = 0; s < NSUB; s++) acc[i][s] = {0.f, 0.f, 0.f, 0.f};

  half8 rA0 = {}, rA1 = {}, nA0 = {}, nA1 = {};
  float rB[BJ] = {}, nBv[BJ] = {};

  auto load_it = [&](int it, half8& A0, half8& A1, float* BW) {
    int tap, kb;
    if (SMODE == 1) { tap = 0; kb = it; }
    else if (KBI == 1) { tap = it; kb = 0; }
    else { tap = it / KBI; kb = it - tap * KBI; }
    int toz, toy, tox, wtap;
    if (SMODE == 1) {
      toz = p_toz; toy = p_toy; tox = p_tox; wtap = p_wtap;
    } else if (SMODE == 0) {
      const int tt = tap0 + tap;
      const int iz = tt / 9;
      const int rem = tt - iz * 9;
      const int iy = rem / 3;
      const int ix = rem - iy * 3;
      toz = iz; toy = iy; tox = ix;
      wtap = tt;
    } else {
      const int iz = tap >> (shx2 + shy2);
      const int rem = tap & ((1 << (shx2 + shy2)) - 1);
      const int iy = rem >> shx2;
      const int ix = rem & ((1 << shx2) - 1);
      toz = clz ? 1 : iz; toy = cly ? 1 : iy; tox = clx ? 1 : ix;
      const int wz = clz ? 1 : 2 * iz, wy = cly ? 1 : 2 * iy,
                wx = clx ? 1 : 2 * ix;
      wtap = (wz * 3 + wy) * 3 + wx;
    }
    const int kof0 = cig * CICHUNK + kb * KB;
    const size_t pb =
        ((size_t)(((u0z + toz + spz) * PS + (u0y + toy + spy)) * PS +
                  (u0x + tox + spx))) * CIN + kof0 + skq * 8;
    A0 = *(const half8*)(P + pb);
    if (M == 128)
      A1 = *(const half8*)(P + pb + (size_t)4 * PS * PS * CIN);
    const float* wb =
        W + ((size_t)wtap * CIN + kof0 + k0B) * COUT + n_base + nB;
#pragma unroll
    for (int j = 0; j < BJ; j++) BW[j] = wb[(size_t)j * COUT];
  };

  load_it(0, rA0, rA1, rB);

  for (int it = 0; it < NIT; ++it) {
    *(half8*)&As[sp][skq * 8] = rA0;
    if (M == 128) *(half8*)&As[sp + 64][skq * 8] = rA1;
    if (BJ == 8) {
      half8 hb;
#pragma unroll
      for (int j = 0; j < 8; j++) hb[j] = (_Float16)rB[j];
      *(half8*)&Bs[nB][k0B] = hb;
    } else {
      half4v hb;
#pragma unroll
      for (int j = 0; j < 4; j++) hb[j] = (_Float16)rB[j];
      *(half4v*)&Bs[nB][k0B] = hb;
    }
    __syncthreads();
    if (it + 1 < NIT) load_it(it + 1, nA0, nA1, nBv);
    half8 a0 = *(const half8*)&As[m0w + fr][fq * 8];
    half8 a1 = *(const half8*)&As[m0w + 16 + fr][fq * 8];
#pragma unroll
    for (int s = 0; s < NSUB; s++) {
      half8 b = *(const half8*)&Bs[n0w + s * 16 + fr][fq * 8];
      acc[0][s] = __builtin_amdgcn_mfma_f32_16x16x32_f16(a0, b, acc[0][s], 0, 0, 0);
      acc[1][s] = __builtin_amdgcn_mfma_f32_16x16x32_f16(a1, b, acc[1][s], 0, 0, 0);
    }
    __syncthreads();
    rA0 = nA0;
    rA1 = nA1;
#pragma unroll
    for (int j = 0; j < BJ; j++) rB[j] = nBv[j];
  }

#pragma unroll
  for (int i = 0; i < 2; i++) {
#pragma unroll
    for (int r = 0; r < 4; r++) {
      const int m = m0w + i * 16 + fq * 4 + r;
      const int mz = m >> 4, my = (m >> 2) & 3, mx = m & 3;
      if (STORE_MODE == 2) {
        const int oz = 2 * (u0z + mz) + clz;
        const int oy = 2 * (u0y + my) + cly;
        const int ox = 2 * (u0x + mx) + clx;
        _Float16* o = (_Float16*)Optr +
            ((size_t)(((oz + 1) * (S + 2) + (oy + 1)) * (S + 2) + (ox + 1))) *
                COUT + n_base + n0w;
#pragma unroll
        for (int s = 0; s < NSUB; s++)
          o[s * 16 + fr] = (_Float16)fmaxf(acc[i][s][r], 0.f);
      } else {
        const size_t pos =
            ((size_t)((u0z + mz) * SOUTU + (u0y + my))) * SOUTU + (u0x + mx);
        float* o = (float*)Optr + ((size_t)jspl * U3 + pos) * COUT + n_base +
                   n0w;
#pragma unroll
        for (int s = 0; s < NSUB; s++) o[s * 16 + fr] = acc[i][s][r];
      }
    }
  }
}

template <int CICHUNK, int CIN, int COUT, int NTILE, int TZ, int SOUTU,
          int PS, int SMODE, int TAPG, int STORE_MODE>
__global__ __launch_bounds__(256) void conv_mfma_k(
    const _Float16* __restrict__ P, const float* __restrict__ W,
    void* __restrict__ Optr) {
  conv_body<CICHUNK, CIN, COUT, NTILE, TZ, SOUTU, PS, SMODE, TAPG, STORE_MODE>(
      blockIdx.x, blockIdx.y, blockIdx.z, P, W, Optr);
}

template <int CICHUNK, int CIN, int COUT, int NTILE, int TZ, int SOUTU,
          int PS, int SMODE, int TAPG, int STORE_MODE, int REP>
__global__ __launch_bounds__(256) void conv_probe_k(
    const _Float16* __restrict__ P, const float* __restrict__ W,
    void* __restrict__ Optr) {
  for (int r = 0; r < REP; ++r) {
    conv_body<CICHUNK, CIN, COUT, NTILE, TZ, SOUTU, PS, SMODE, TAPG,
              STORE_MODE>(blockIdx.x, blockIdx.y, blockIdx.z, P, W, Optr);
    asm volatile("" ::: "memory");
  }
}

// Layer 6 body: 32 -> 1 channels (128 threads/block).
__device__ __forceinline__ void conv6_body(const _Float16* __restrict__ P,
                                           const float* __restrict__ W6,
                                           float* __restrict__ O) {
  __shared__ __align__(16) float w[864];  // 27*32
  for (int i = threadIdx.x; i < 864; i += 128) w[i] = W6[i];
  __syncthreads();
  int idx = blockIdx.x * 128 + threadIdx.x;  // 32768 outputs
  int x = idx & 31, y = (idx >> 5) & 31, z = idx >> 10;
  float a = 0.f;
  for (int dz = 0; dz < 3; dz++)
    for (int dy = 0; dy < 3; dy++)
      for (int dx = 0; dx < 3; dx++) {
        const _Float16* p =
            P + (size_t)(((z + dz) * 34 + (y + dy)) * 34 + (x + dx)) * 32;
        const float* ww = &w[((dz * 3 + dy) * 3 + dx) * 32];
#pragma unroll
        for (int c = 0; c < 32; c += 8) {
          half8 pv = *(const half8*)&p[c];
#pragma unroll
          for (int u = 0; u < 8; u++) a += (float)pv[u] * ww[c + u];
        }
      }
  O[idx] = a;
}

__global__ __launch_bounds__(128) void conv6_k(const _Float16* __restrict__ P,
                                               const float* __restrict__ W6,
                                               float* __restrict__ O) {
  conv6_body(P, W6, O);
}

template <int REP>
__global__ __launch_bounds__(128) void conv6_probe_k(
    const _Float16* __restrict__ P, const float* __restrict__ W6,
    float* __restrict__ O) {
  for (int r = 0; r < REP; ++r) {
    conv6_body(P, W6, O);
    __syncthreads();
    asm volatile("" ::: "memory");
  }
}

extern "C" void kernel_launch(void* const* d_in, const int* in_sizes, int n_in,
                              void* d_out, int out_size, void* d_ws,
                              size_t ws_size, hipStream_t stream) {
  const float* x  = (const float*)d_in[0];
  const float* w1 = (const float*)d_in[1];
  const float* w2 = (const float*)d_in[2];
  const float* w3 = (const float*)d_in[3];
  const float* w4 = (const float*)d_in[4];
  const float* w5 = (const float*)d_in[5];
  const float* w6 = (const float*)d_in[6];
  float* out = (float*)d_out;

  // fp32 partial slabs
  float* Q1 = (float*)d_ws;                  // 108 * 64   * 512 = 3538944
  float* Q2 = Q1 + 3538944;                  // 24  * 512  * 256 = 3145728
  float* Q3 = Q2 + 3145728;                  // 54  * 512  * 128 = 3538944
  float* Q4 = Q3 + 3538944;                  // 12  * 4096 * 64  = 3145728
  // fp16 padded activations
  _Float16* P1 = (_Float16*)(Q4 + 3145728);  // 5^3  * 1024 = 128000
  _Float16* P2 = P1 + 128000;                // 10^3 * 512  = 512000
  _Float16* P3 = P2 + 512000;                // 9^3  * 256  = 186624
  _Float16* P4 = P3 + 186624;                // 18^3 * 128  = 746496
  _Float16* P5 = P4 + 746496;                // 17^3 * 64   = 314432
  _Float16* P6 = P5 + 314432;                // 34^3 * 32   = 1257728
  float* scratchF = (float*)(P6 + 1257728);  // probe-only sink (128 KB)

  // ---- real pipeline (R10 verbatim) ----
  pad_x_k<<<500, 256, 0, stream>>>(x, P1);
  conv_mfma_k<256, 1024, 512, 64, 4, 4, 5, 1, 0, 3>
      <<<dim3(27, 8, 4), 256, 0, stream>>>(P1, w1, Q1);
  red_k<8, 512, 1, 4, 10><<<500, 256, 0, stream>>>(Q1, P2);
  conv_mfma_k<64, 512, 256, 64, 8, 8, 10, 0, 9, 3>
      <<<dim3(4, 4, 24), 256, 0, stream>>>(P2, w2, Q2);
  red_k<8, 256, 0, 24, 9><<<183, 256, 0, stream>>>(Q2, P3);
  conv_mfma_k<128, 256, 128, 64, 8, 8, 9, 1, 0, 3>
      <<<dim3(108, 2, 2), 256, 0, stream>>>(P3, w3, Q3);
  red_k<16, 128, 1, 2, 18><<<729, 256, 0, stream>>>(Q3, P4);
  conv_mfma_k<32, 128, 64, 64, 8, 16, 18, 0, 9, 3>
      <<<dim3(32, 1, 12), 256, 0, stream>>>(P4, w4, Q4);
  red4z_k<<<923, 256, 0, stream>>>(Q4, P5, P6);
  conv_mfma_k<64, 64, 32, 32, 8, 16, 17, 2, 0, 2>
      <<<dim3(256, 1, 1), 256, 0, stream>>>(P5, w5, P6);
  conv6_k<<<256, 128, 0, stream>>>(P6, w6, out);

  // ---- probes (measurement only; outputs are dead or scratch) ----
  constexpr int REP = 24;
  conv_probe_k<256, 1024, 512, 64, 4, 4, 5, 1, 0, 3, REP>
      <<<dim3(27, 8, 4), 256, 0, stream>>>(P1, w1, Q1);
  red_probe_k<8, 512, 1, 4, 10, REP><<<500, 256, 0, stream>>>(Q1, P2);
  conv_probe_k<64, 512, 256, 64, 8, 8, 10, 0, 9, 3, REP>
      <<<dim3(4, 4, 24), 256, 0, stream>>>(P2, w2, Q2);
  red_probe_k<8, 256, 0, 24, 9, REP><<<183, 256, 0, stream>>>(Q2, P3);
  conv_probe_k<128, 256, 128, 64, 8, 8, 9, 1, 0, 3, REP>
      <<<dim3(108, 2, 2), 256, 0, stream>>>(P3, w3, Q3);
  red_probe_k<16, 128, 1, 2, 18, REP><<<729, 256, 0, stream>>>(Q3, P4);
  conv_probe_k<32, 128, 64, 64, 8, 16, 18, 0, 9, 3, REP>
      <<<dim3(32, 1, 12), 256, 0, stream>>>(P4, w4, Q4);
  red_probe_k<16, 64, 0, 12, 17, REP><<<308, 256, 0, stream>>>(Q4, P5);
  conv_probe_k<64, 64, 32, 32, 8, 16, 17, 2, 0, 2, REP>
      <<<dim3(256, 1, 1), 256, 0, stream>>>(P5, w5, P6);
  conv6_probe_k<REP><<<256, 128, 0, stream>>>(P6, w6, scratchF);

  (void)in_sizes; (void)n_in; (void)out_size; (void)ws_size;
}

// Round 8
// 206.818 us; speedup vs baseline: 7.8965x; 7.8965x over previous
//
#include <hip/hip_runtime.h>

typedef _Float16 half8 __attribute__((ext_vector_type(8)));
typedef _Float16 half4v __attribute__((ext_vector_type(4)));
typedef float floatx4 __attribute__((ext_vector_type(4)));

// ---------------------------------------------------------------------------
// Decoder: 6 conv_transpose3d (JAX SAME, no kernel flip), fp16 MFMA.
// R13 = R12 with the WM==2 n-split bug fixed. R12's failure: with TZ=4,
// conv5 (NTILE=32) took the WM==2 path whose n0w = (wave&1)*32 assumed a
// >=64-row B tile -> OOB Bs reads + writes into columns 32..47 of a 32-ch
// layer. Fix: n0w = (wave&1)*(NTILE/2) (identical for NTILE=64; 32x16
// sub-tiles for NTILE=32). Per-output K-accumulation order unchanged.
// R12 deltas retained: TZ=4 (M=64) for conv2/3/4/5 (grid doubles, occupancy
// 1.5->3.0 blocks/CU on the worst body conv2); GX-fused conv1; red4z fusion;
// conv6 at 256x128.
// ---------------------------------------------------------------------------

// Reduce partials -> ReLU -> fp16 -> padded next-layer input (borders = 0).
template <int POS, int COUT, int S2IN, int NSPL, int PS>
__device__ __forceinline__ void red_body(int vb, const float* __restrict__ Pp,
                                         _Float16* __restrict__ P) {
  constexpr int C4 = COUT / 4;
  constexpr size_t U3 =
      S2IN ? (size_t)(POS / 2) * (POS / 2) * (POS / 2) : (size_t)POS * POS * POS;
  int idx = vb * 256 + threadIdx.x;
  if (idx >= PS * PS * PS * C4) return;
  const int co = (idx % C4) * 4;
  const int r = idx / C4;
  const int px = r % PS, py = (r / PS) % PS, pz = r / (PS * PS);
  const int ix = px - 1, iy = py - 1, iz = pz - 1;
  float4 s = make_float4(0.f, 0.f, 0.f, 0.f);
  if ((unsigned)ix < (unsigned)POS && (unsigned)iy < (unsigned)POS &&
      (unsigned)iz < (unsigned)POS) {
    int j0, j1;
    size_t upos;
    if (S2IN) {
      const int pf[8] = {0, 8, 12, 16, 18, 22, 24, 26};
      const int tc[8] = {8, 4, 4, 2, 4, 2, 2, 1};
      const int cls = ((iz & 1) << 2) | ((iy & 1) << 1) | (ix & 1);
      j0 = pf[cls] * NSPL;
      j1 = j0 + tc[cls] * NSPL;
      constexpr int U = POS / 2;
      upos = ((size_t)(iz >> 1) * U + (iy >> 1)) * U + (ix >> 1);
    } else {
      j0 = 0;
      j1 = NSPL;
      upos = ((size_t)iz * POS + iy) * POS + ix;
    }
    const float* base = Pp + upos * COUT + co;
    for (int j = j0; j < j1; j++) {
      float4 v = *(const float4*)(base + (size_t)j * U3 * COUT);
      s.x += v.x; s.y += v.y; s.z += v.z; s.w += v.w;
    }
  }
  half4v h;
  h[0] = (_Float16)fmaxf(s.x, 0.f);
  h[1] = (_Float16)fmaxf(s.y, 0.f);
  h[2] = (_Float16)fmaxf(s.z, 0.f);
  h[3] = (_Float16)fmaxf(s.w, 0.f);
  *(half4v*)(P + (size_t)idx * 4) = h;
}

template <int POS, int COUT, int S2IN, int NSPL, int PS>
__global__ __launch_bounds__(256) void red_k(const float* __restrict__ Pp,
                                             _Float16* __restrict__ P) {
  red_body<POS, COUT, S2IN, NSPL, PS>(blockIdx.x, Pp, P);
}

// red4 + P6 zero fused: blocks < 308 do red4 (Q4 -> P5); blocks >= 308 zero
// P6 (615 blocks cover 157216 half8s = 34^3*32 halfs).
__global__ __launch_bounds__(256) void red4z_k(const float* __restrict__ Q4,
                                               _Float16* __restrict__ P5,
                                               _Float16* __restrict__ P6) {
  if (blockIdx.x < 308) {
    red_body<16, 64, 0, 12, 17>(blockIdx.x, Q4, P5);
  } else {
    int i = (blockIdx.x - 308) * 256 + threadIdx.x;
    if (i < 157216) ((half8*)P6)[i] = half8{};
  }
}

// MFMA implicit-GEMM conv. Block = 256 threads = 4 waves. SMODE: 0 = stride1
// tap-groups, 1 = stride2 (class,tap) pairs in blockIdx.x, 2 = stride2
// class-loop. STORE_MODE: 2 = fp16 ReLU store into padded (S+2)^3 buffer,
// 3 = fp32 partial slab store. GX: 1 = A gathered from fp32 NCDHW Xg
// (SOUTU^3 spatial, zero-pad on the fly) instead of fp16 P.
template <int CICHUNK, int CIN, int COUT, int NTILE, int TZ, int SOUTU,
          int PS, int SMODE, int TAPG, int STORE_MODE, int GX>
__global__ __launch_bounds__(256) void conv_mfma_k(
    const _Float16* __restrict__ P, const float* __restrict__ W,
    void* __restrict__ Optr, const float* __restrict__ Xg) {
  constexpr int M = TZ * 16;               // 64 or 128
  constexpr bool S2 = (SMODE != 0);
  constexpr int MTZ = SOUTU / TZ;
  constexpr int MTXY = SOUTU / 4;
  constexpr int MT3 = MTZ * MTXY * MTXY;
  constexpr int KB = 32;
  constexpr int KP = 40;
  constexpr int KBI = CICHUNK / KB;
  constexpr int NCI = CIN / CICHUNK;
  constexpr int S = S2 ? 2 * SOUTU : SOUTU;
  constexpr int WM = (M == 128) ? 4 : 2;   // waves along m
  constexpr int NH = (WM == 4) ? NTILE : (NTILE / 2);  // cols per wave
  constexpr int NSUB = NH / 16;
  constexpr int BJ = KB * NTILE / 256;     // B fp32 loads per thread
  constexpr size_t U3 = (size_t)SOUTU * SOUTU * SOUTU;

  __shared__ __align__(16) _Float16 As[M][KP];
  __shared__ __align__(16) _Float16 Bs[NTILE][KP];

  int bx = blockIdx.x;
  int cls = 0, tap0 = 0, cig = blockIdx.z, jspl = 0;
  int p_toz = 0, p_toy = 0, p_tox = 0, p_wtap = 0;
  if (SMODE == 0) {
    const int tg = cig / NCI;
    cig -= tg * NCI;
    tap0 = tg * TAPG;
    jspl = blockIdx.z;                     // tg*NCI + cig
  } else if (SMODE == 1) {
    const int p = bx / MT3;
    bx -= p * MT3;
    jspl = p * NCI + cig;
    cls = (p >= 8) + (p >= 12) + (p >= 16) + (p >= 18) + (p >= 22) +
          (p >= 24) + (p >= 26);
    const int pf = cls == 0 ? 0 : cls == 1 ? 8 : cls == 2 ? 12
                 : cls == 3 ? 16 : cls == 4 ? 18 : cls == 5 ? 22
                 : cls == 6 ? 24 : 26;
    const int tl = p - pf;
    const int lz = (cls >> 2) & 1, ly = (cls >> 1) & 1, lx = cls & 1;
    const int shx = lx ? 0 : 1, shy = ly ? 0 : 1;
    const int iz = tl >> (shx + shy);
    const int rem = tl & ((1 << (shx + shy)) - 1);
    const int iy = rem >> shx;
    const int ix = rem & ((1 << shx) - 1);
    p_toz = lz ? 1 : iz;
    p_toy = ly ? 1 : iy;
    p_tox = lx ? 1 : ix;
    const int wz = lz ? 1 : 2 * iz, wy = ly ? 1 : 2 * iy,
              wx = lx ? 1 : 2 * ix;
    p_wtap = (wz * 3 + wy) * 3 + wx;
  } else {
    cls = bx / MT3;
    bx -= cls * MT3;
  }
  const int clz = (cls >> 2) & 1, cly = (cls >> 1) & 1, clx = cls & 1;

  const int u0z = (bx / (MTXY * MTXY)) * TZ;
  const int u0y = ((bx / MTXY) % MTXY) * 4;
  const int u0x = (bx % MTXY) * 4;
  const int n_base = blockIdx.y * NTILE;

  const int t = threadIdx.x;
  const int lane = t & 63;
  const int wave = t >> 6;

  // A staging: thread t -> position sp (4x4x4 z-major), k-chunk skq
  const int skq = t & 3;
  const int sp = t >> 2;
  const int spx = sp & 3, spy = (sp >> 2) & 3, spz = sp >> 4;
  // B staging: thread t -> n-row nB, k range [k0B, k0B+BJ)
  const int nB = t & (NTILE - 1);
  const int k0B = (t / NTILE) * BJ;
  // compute mapping
  const int m0w = (WM == 4) ? wave * 32 : (wave >> 1) * 32;
  const int n0w = (WM == 4) ? 0 : (wave & 1) * NH;
  const int fr = lane & 15;
  const int fq = lane >> 4;

  const int cz = S2 ? (clz ? 1 : 2) : 3;
  const int cy = S2 ? (cly ? 1 : 2) : 3;
  const int cx = S2 ? (clx ? 1 : 2) : 3;
  const int shx2 = clx ? 0 : 1, shy2 = cly ? 0 : 1;

  int NIT;
  if (SMODE == 0) NIT = TAPG * KBI;
  else if (SMODE == 1) NIT = KBI;
  else NIT = cz * cy * cx * KBI;

  floatx4 acc[2][NSUB];
#pragma unroll
  for (int i = 0; i < 2; i++)
#pragma unroll
    for (int s = 0; s < NSUB; s++) acc[i][s] = {0.f, 0.f, 0.f, 0.f};

  half8 rA0 = {}, rA1 = {}, nA0 = {}, nA1 = {};
  float rB[BJ] = {}, nBv[BJ] = {};

  auto load_it = [&](int it, half8& A0, half8& A1, float* BW) {
    int tap, kb;
    if (SMODE == 1) { tap = 0; kb = it; }
    else if (KBI == 1) { tap = it; kb = 0; }
    else { tap = it / KBI; kb = it - tap * KBI; }
    int toz, toy, tox, wtap;
    if (SMODE == 1) {
      toz = p_toz; toy = p_toy; tox = p_tox; wtap = p_wtap;
    } else if (SMODE == 0) {
      const int tt = tap0 + tap;
      const int iz = tt / 9;
      const int rem = tt - iz * 9;
      const int iy = rem / 3;
      const int ix = rem - iy * 3;
      toz = iz; toy = iy; tox = ix;
      wtap = tt;
    } else {
      const int iz = tap >> (shx2 + shy2);
      const int rem = tap & ((1 << (shx2 + shy2)) - 1);
      const int iy = rem >> shx2;
      const int ix = rem & ((1 << shx2) - 1);
      toz = clz ? 1 : iz; toy = cly ? 1 : iy; tox = clx ? 1 : ix;
      const int wz = clz ? 1 : 2 * iz, wy = cly ? 1 : 2 * iy,
                wx = clx ? 1 : 2 * ix;
      wtap = (wz * 3 + wy) * 3 + wx;
    }
    const int kof0 = cig * CICHUNK + kb * KB;
    if (GX) {
      // gather fp32 NCDHW x (SOUTU^3) with zero pad; M==64 here, A1 unused
      const int gz = u0z + toz + spz - 1;
      const int gy = u0y + toy + spy - 1;
      const int gxx = u0x + tox + spx - 1;
      const int c0 = kof0 + skq * 8;
      if ((unsigned)gxx < (unsigned)SOUTU && (unsigned)gy < (unsigned)SOUTU &&
          (unsigned)gz < (unsigned)SOUTU) {
        const float* xb = Xg + (size_t)c0 * (SOUTU * SOUTU * SOUTU) +
                          (gz * SOUTU + gy) * SOUTU + gxx;
#pragma unroll
        for (int u = 0; u < 8; u++)
          A0[u] = (_Float16)xb[(size_t)u * (SOUTU * SOUTU * SOUTU)];
      } else {
#pragma unroll
        for (int u = 0; u < 8; u++) A0[u] = (_Float16)0.f;
      }
    } else {
      const size_t pb =
          ((size_t)(((u0z + toz + spz) * PS + (u0y + toy + spy)) * PS +
                    (u0x + tox + spx))) * CIN + kof0 + skq * 8;
      A0 = *(const half8*)(P + pb);
      if (M == 128)
        A1 = *(const half8*)(P + pb + (size_t)4 * PS * PS * CIN);
    }
    const float* wb =
        W + ((size_t)wtap * CIN + kof0 + k0B) * COUT + n_base + nB;
#pragma unroll
    for (int j = 0; j < BJ; j++) BW[j] = wb[(size_t)j * COUT];
  };

  load_it(0, rA0, rA1, rB);

  for (int it = 0; it < NIT; ++it) {
    *(half8*)&As[sp][skq * 8] = rA0;
    if (M == 128) *(half8*)&As[sp + 64][skq * 8] = rA1;
    if (BJ == 8) {
      half8 hb;
#pragma unroll
      for (int j = 0; j < 8; j++) hb[j] = (_Float16)rB[j];
      *(half8*)&Bs[nB][k0B] = hb;
    } else {
      half4v hb;
#pragma unroll
      for (int j = 0; j < 4; j++) hb[j] = (_Float16)rB[j];
      *(half4v*)&Bs[nB][k0B] = hb;
    }
    __syncthreads();
    if (it + 1 < NIT) load_it(it + 1, nA0, nA1, nBv);
    half8 a0 = *(const half8*)&As[m0w + fr][fq * 8];
    half8 a1 = *(const half8*)&As[m0w + 16 + fr][fq * 8];
#pragma unroll
    for (int s = 0; s < NSUB; s++) {
      half8 b = *(const half8*)&Bs[n0w + s * 16 + fr][fq * 8];
      acc[0][s] = __builtin_amdgcn_mfma_f32_16x16x32_f16(a0, b, acc[0][s], 0, 0, 0);
      acc[1][s] = __builtin_amdgcn_mfma_f32_16x16x32_f16(a1, b, acc[1][s], 0, 0, 0);
    }
    __syncthreads();
    rA0 = nA0;
    rA1 = nA1;
#pragma unroll
    for (int j = 0; j < BJ; j++) rB[j] = nBv[j];
  }

#pragma unroll
  for (int i = 0; i < 2; i++) {
#pragma unroll
    for (int r = 0; r < 4; r++) {
      const int m = m0w + i * 16 + fq * 4 + r;
      const int mz = m >> 4, my = (m >> 2) & 3, mx = m & 3;
      if (STORE_MODE == 2) {
        const int oz = 2 * (u0z + mz) + clz;
        const int oy = 2 * (u0y + my) + cly;
        const int ox = 2 * (u0x + mx) + clx;
        _Float16* o = (_Float16*)Optr +
            ((size_t)(((oz + 1) * (S + 2) + (oy + 1)) * (S + 2) + (ox + 1))) *
                COUT + n_base + n0w;
#pragma unroll
        for (int s = 0; s < NSUB; s++)
          o[s * 16 + fr] = (_Float16)fmaxf(acc[i][s][r], 0.f);
      } else {
        const size_t pos =
            ((size_t)((u0z + mz) * SOUTU + (u0y + my))) * SOUTU + (u0x + mx);
        float* o = (float*)Optr + ((size_t)jspl * U3 + pos) * COUT + n_base +
                   n0w;
#pragma unroll
        for (int s = 0; s < NSUB; s++) o[s * 16 + fr] = acc[i][s][r];
      }
    }
  }
}

// Layer 6: 32 -> 1 channels, per-output dot product from padded fp16 P6.
__global__ __launch_bounds__(128) void conv6_k(const _Float16* __restrict__ P,
                                               const float* __restrict__ W6,
                                               float* __restrict__ O) {
  __shared__ __align__(16) float w[864];  // 27*32
  for (int i = threadIdx.x; i < 864; i += 128) w[i] = W6[i];
  __syncthreads();
  int idx = blockIdx.x * 128 + threadIdx.x;  // 32768 outputs
  int x = idx & 31, y = (idx >> 5) & 31, z = idx >> 10;
  float a = 0.f;
  for (int dz = 0; dz < 3; dz++)
    for (int dy = 0; dy < 3; dy++)
      for (int dx = 0; dx < 3; dx++) {
        const _Float16* p =
            P + (size_t)(((z + dz) * 34 + (y + dy)) * 34 + (x + dx)) * 32;
        const float* ww = &w[((dz * 3 + dy) * 3 + dx) * 32];
#pragma unroll
        for (int c = 0; c < 32; c += 8) {
          half8 pv = *(const half8*)&p[c];
#pragma unroll
          for (int u = 0; u < 8; u++) a += (float)pv[u] * ww[c + u];
        }
      }
  O[idx] = a;
}

extern "C" void kernel_launch(void* const* d_in, const int* in_sizes, int n_in,
                              void* d_out, int out_size, void* d_ws,
                              size_t ws_size, hipStream_t stream) {
  const float* x  = (const float*)d_in[0];
  const float* w1 = (const float*)d_in[1];
  const float* w2 = (const float*)d_in[2];
  const float* w3 = (const float*)d_in[3];
  const float* w4 = (const float*)d_in[4];
  const float* w5 = (const float*)d_in[5];
  const float* w6 = (const float*)d_in[6];
  float* out = (float*)d_out;

  // fp32 partial slabs
  float* Q1 = (float*)d_ws;                  // 108 * 64   * 512 = 3538944
  float* Q2 = Q1 + 3538944;                  // 24  * 512  * 256 = 3145728
  float* Q3 = Q2 + 3145728;                  // 54  * 512  * 128 = 3538944
  float* Q4 = Q3 + 3538944;                  // 12  * 4096 * 64  = 3145728
  // fp16 padded activations (P1 slot retained, unused with GX)
  _Float16* P1 = (_Float16*)(Q4 + 3145728);  // 5^3  * 1024 = 128000 (unused)
  _Float16* P2 = P1 + 128000;                // 10^3 * 512  = 512000
  _Float16* P3 = P2 + 512000;                // 9^3  * 256  = 186624
  _Float16* P4 = P3 + 186624;                // 18^3 * 128  = 746496
  _Float16* P5 = P4 + 746496;                // 17^3 * 64   = 314432
  _Float16* P6 = P5 + 314432;                // 34^3 * 32   = 1257728

  // L1: 1024->512, 4^3 -> 8^3, s2; A gathered from x directly (GX=1)
  conv_mfma_k<256, 1024, 512, 64, 4, 4, 5, 1, 0, 3, 1>
      <<<dim3(27, 8, 4), 256, 0, stream>>>(nullptr, w1, Q1, x);
  red_k<8, 512, 1, 4, 10><<<500, 256, 0, stream>>>(Q1, P2);
  // L2: 512->256, 8^3, s1; TZ=4 -> grid(8,4,24)=768 blocks (3.0/CU)
  conv_mfma_k<64, 512, 256, 64, 4, 8, 10, 0, 9, 3, 0>
      <<<dim3(8, 4, 24), 256, 0, stream>>>(P2, w2, Q2, nullptr);
  red_k<8, 256, 0, 24, 9><<<183, 256, 0, stream>>>(Q2, P3);
  // L3: 256->128, 8^3 -> 16^3, s2; TZ=4 -> grid(216,2,2)=864 blocks
  conv_mfma_k<128, 256, 128, 64, 4, 8, 9, 1, 0, 3, 0>
      <<<dim3(216, 2, 2), 256, 0, stream>>>(P3, w3, Q3, nullptr);
  red_k<16, 128, 1, 2, 18><<<729, 256, 0, stream>>>(Q3, P4);
  // L4: 128->64, 16^3, s1; TZ=4 -> grid(64,1,12)=768 blocks
  conv_mfma_k<32, 128, 64, 64, 4, 16, 18, 0, 9, 3, 0>
      <<<dim3(64, 1, 12), 256, 0, stream>>>(P4, w4, Q4, nullptr);
  // red4 + P6 zero fused (308 red blocks + 615 zero blocks)
  red4z_k<<<923, 256, 0, stream>>>(Q4, P5, P6);
  // L5: 64->32, 16^3 -> 32^3, s2 class-loop; TZ=4 -> grid(512,1,1)
  conv_mfma_k<64, 64, 32, 32, 4, 16, 17, 2, 0, 2, 0>
      <<<dim3(512, 1, 1), 256, 0, stream>>>(P5, w5, P6, nullptr);
  // L6: 32->1, 32^3, s1, no final ReLU
  conv6_k<<<256, 128, 0, stream>>>(P6, w6, out);

  (void)in_sizes; (void)n_in; (void)out_size; (void)ws_size;
}